// Round 11
// baseline (45.459 us; speedup 1.0000x reference)
//
#include <hip/hip_runtime.h>
#include <hip/hip_bf16.h>
#include <hip/hip_fp16.h>

// Problem constants (from reference)
#define IMG_H 512
#define IMG_W 512
#define N_VIEWS 180
#define N_DET 512
#define N_SAMPLES 512

#define N_RAYS (N_VIEWS * N_DET)          // 92160
#define IMG_N (IMG_H * IMG_W)             // 262144

// Row-pair fp16 grids, 8-px zero pad ring, TWO layouts (see R10):
//  Rrm[(iy+8)*QDIM + (ix+8)] = half2{ I[iy][ix], I[iy+1][ix] }   (4B/cell)
//  Tcm[(ix+8)*QDIM + (iy+8)] = half2{ I[iy][ix], I[iy][ix+1] }   (transposed)
// Key property: a bilinear sample touches exactly ONE table row (the pair
// holds both y-taps) -> LDS banding over table rows is clean.
#define QPAD 8
#define QDIM (IMG_W + 1 + 2 * QPAD)       // 529
#define R_N (QDIM * QDIM)                 // 279841
#define R_BYTES ((size_t)R_N * 4)         // ~1.07 MiB
#define R_BYTES_AL ((R_BYTES + 255) & ~(size_t)255)
#define RAYINFO_BYTES ((size_t)N_RAYS * 32)

#define BROWS 33
#define NBANDS 16                          // 16*33 = 528 >= all sampled rows
#define LDSN (BROWS * QDIM)                // 17457 dwords
#define LDS_BYTES (LDSN * 4)               // 69828 B

#define PACK_BLOCKS ((R_N + 255) / 256)   // 1094
#define SETUP_BLOCKS (N_RAYS / 256)       // 360

// ---------------------------------------------------------------------------
// k1 (merged prep), grid = 2*PACK_BLOCKS + SETUP_BLOCKS:
//   part 0: pack Rrm (coalesced) + emit relu(x+reco)
//   part 1: pack Tcm (transposed reads from x,reco; linear writes)
//   part 2: per-ray setup (coords swapped for T-views) ->
//           RA={dx,dy,bx,by}, RB={segscl,s0,len,512/dy}; zero sino.
// ---------------------------------------------------------------------------
__global__ __launch_bounds__(256) void prep_kernel(
        const float* __restrict__ x, const float* __restrict__ r,
        unsigned* __restrict__ Rrm, unsigned* __restrict__ Tcm,
        float* __restrict__ relu_out,
        const float* __restrict__ src_pos,
        const float* __restrict__ det_center,
        const float* __restrict__ det_u,
        float4* __restrict__ RA, float4* __restrict__ RB,
        float* __restrict__ sino) {
    const int b = blockIdx.x;
    if (b < PACK_BLOCKS) {
        int i = b * 256 + threadIdx.x;
        if (i >= R_N) return;
        int row = i / QDIM;
        int col = i - row * QDIM;
        int yy = row - QPAD;
        int xx = col - QPAD;
        float v0 = 0.f, v1 = 0.f;
        if ((unsigned)xx < (unsigned)IMG_W) {
            if ((unsigned)yy < (unsigned)IMG_H) {
                int idx = yy * IMG_W + xx;
                v0 = x[idx] + r[idx];
            }
            if ((unsigned)(yy + 1) < (unsigned)IMG_H) {
                int idx = (yy + 1) * IMG_W + xx;
                v1 = x[idx] + r[idx];
            }
        }
        __half2 h = __floats2half2_rn(v0, v1);
        Rrm[i] = *reinterpret_cast<unsigned*>(&h);
        if ((unsigned)xx < (unsigned)IMG_W && (unsigned)yy < (unsigned)IMG_H)
            relu_out[yy * IMG_W + xx] = fmaxf(v0, 0.f);
        return;
    }
    if (b < 2 * PACK_BLOCKS) {
        int j = (b - PACK_BLOCKS) * 256 + threadIdx.x;
        if (j >= R_N) return;
        int row = j / QDIM;          // orig x of the pair
        int col = j - row * QDIM;    // orig y
        int rp = row - QPAD;
        int cp = col - QPAD;
        float v0 = 0.f, v1 = 0.f;
        if ((unsigned)cp < (unsigned)IMG_H) {
            int base = cp * IMG_W;
            if ((unsigned)rp < (unsigned)IMG_W)       v0 = x[base + rp] + r[base + rp];
            if ((unsigned)(rp + 1) < (unsigned)IMG_W) v1 = x[base + rp + 1] + r[base + rp + 1];
        }
        __half2 h = __floats2half2_rn(v0, v1);
        Tcm[j] = *reinterpret_cast<unsigned*>(&h);
        return;
    }

    // ---- ray setup ----
    const int rid = (b - 2 * PACK_BLOCKS) * 256 + threadIdx.x;
    const int v   = rid >> 9;
    const int det = rid & 511;

    float sx = src_pos[2 * v];
    float sy = src_pos[2 * v + 1];
    const float ux = det_u[2 * v];
    const float uy = det_u[2 * v + 1];
    const float u  = ((float)det - 255.5f) * 2.0f;   // DET_SPACING = 2
    float ex = det_center[2 * v]     + u * ux;
    float ey = det_center[2 * v + 1] + u * uy;

    const bool useT = fabsf(uy) > fabsf(ux);
    if (useT) {
        float tmp = sx; sx = sy; sy = tmp;
        tmp = ex; ex = ey; ey = tmp;
    }
    const float dx = ex - sx;
    const float dy = ey - sy;   // dominant component by construction (>~376)
    const float segscl = sqrtf(dx * dx + dy * dy) * (1.0f / (float)N_SAMPLES);

    const float lo = -256.5f, hi = 256.5f;
    float t0 = 0.f, t1 = 1.f;
    if (fabsf(dx) > 1e-12f) {
        float ta = (lo - sx) / dx, tb = (hi - sx) / dx;
        t0 = fmaxf(t0, fminf(ta, tb));
        t1 = fminf(t1, fmaxf(ta, tb));
    } else if (sx <= lo || sx >= hi) {
        t1 = -1.f;
    }
    if (fabsf(dy) > 1e-12f) {
        float ta = (lo - sy) / dy, tb = (hi - sy) / dy;
        t0 = fmaxf(t0, fminf(ta, tb));
        t1 = fminf(t1, fmaxf(ta, tb));
    } else if (sy <= lo || sy >= hi) {
        t1 = -1.f;
    }
    int s0 = 0, len = 0;
    if (t1 >= t0) {
        s0 = max(0, (int)floorf(t0 * (float)N_SAMPLES - 0.5f) - 1);
        int s1 = min(N_SAMPLES - 1, (int)ceilf(t1 * (float)N_SAMPLES - 0.5f) + 1);
        len = s1 - s0 + 1;
        if (len < 0) len = 0;
    }
    RA[rid] = make_float4(dx, dy, sx + 255.5f + (float)QPAD,
                                  sy + 255.5f + (float)QPAD);
    RB[rid] = make_float4(segscl, (float)s0, (float)len,
                          (float)N_SAMPLES / dy);
    sino[rid] = 0.f;
}

// ---------------------------------------------------------------------------
// k2: banded fan-beam projection. Block = (band, view), 1024 threads.
//   Stage band (33 table rows, 68.2 KiB) into LDS, then 512 dets x 2
//   sample-offsets walk their in-band sample sub-range, gathering from LDS
//   (DS pipe, ~4-6 cy/wave vs ~64 on the TCP scatter path).
//   Bands partition samples exactly via the per-sample predicate.
// ---------------------------------------------------------------------------
__global__ __launch_bounds__(1024, 8) void fanproj_band_kernel(
        const unsigned* __restrict__ Rrm, const unsigned* __restrict__ Tcm,
        const float* __restrict__ det_u,
        const float4* __restrict__ RA, const float4* __restrict__ RB,
        float* __restrict__ sino) {
    extern __shared__ unsigned lds[];
    const int band = blockIdx.x;
    const int v    = blockIdx.y;
    const int tid  = threadIdx.x;

    const bool useT = fabsf(det_u[2 * v + 1]) > fabsf(det_u[2 * v]);
    const unsigned* __restrict__ src = (useT ? Tcm : Rrm) + band * LDSN;

    // ---- stage band to LDS (coalesced dwordx4) ----
    for (int j = tid; j < LDSN / 4; j += 1024) {
        uint4 q;
        __builtin_memcpy(&q, src + 4 * j, 16);
        *reinterpret_cast<uint4*>(&lds[4 * j]) = q;
    }
    if (tid == 0) lds[LDSN - 1] = src[LDSN - 1];
    __syncthreads();

    // ---- sample loop ----
    const int det  = tid >> 1;
    const int soff = tid & 1;
    const int rid  = (v << 9) | det;

    const float4 a = RA[rid];
    const float4 b = RB[rid];
    const float dx = a.x, dy = a.y, bx = a.z, by = a.w;
    const int   s0 = (int)b.y;
    const int   len = (int)b.z;
    const float invstep = b.w;                      // 512/dy

    const float B0f = (float)(band * BROWS);
    const float step = dy * (1.0f / (float)N_SAMPLES);
    const float start = by + 0.5f * step;           // py at s=0

    float loF = (B0f - start) * invstep;
    float hiF = (B0f + (float)BROWS - start) * invstep;
    if (invstep < 0.f) { float tmp = loF; loF = hiF; hiF = tmp; }
    const int sb0 = max(s0, (int)floorf(loF) - 1);
    const int sb1 = min(s0 + len - 1, (int)ceilf(hiF) + 1);

    int s = sb0 + soff;
    float t = ((float)s + 0.5f) * (1.0f / (float)N_SAMPLES);   // exact
    float acc0 = 0.f, acc1 = 0.f;
    for (; s + 2 <= sb1; s += 4) {
        {   // sample s
            const float px = fmaf(t, dx, bx);
            const float pyr = fmaf(t, dy, by) - B0f;
            if (pyr >= 0.f && pyr < (float)BROWS) {
                const float ixf = truncf(px);
                const float iylf = truncf(pyr);
                const float fx = px - ixf;
                const float fy = pyr - iylf;
                const int lin = (int)fmaf(iylf, (float)QDIM, ixf);
                uint2 qw;
                __builtin_memcpy(&qw, &lds[lin], 8);
                const float2 fa = __half22float2(*reinterpret_cast<const __half2*>(&qw.x));
                const float2 fb = __half22float2(*reinterpret_cast<const __half2*>(&qw.y));
                const float gx = 1.f - fx;
                const float h0 = fmaf(fx, fb.x, gx * fa.x);
                const float h1 = fmaf(fx, fb.y, gx * fa.y);
                acc0 = fmaf(1.f - fy, h0, acc0);
                acc0 = fmaf(fy, h1, acc0);
            }
        }
        {   // sample s+2
            const float t2 = t + 0.00390625f;                  // +2/512
            const float px = fmaf(t2, dx, bx);
            const float pyr = fmaf(t2, dy, by) - B0f;
            if (pyr >= 0.f && pyr < (float)BROWS) {
                const float ixf = truncf(px);
                const float iylf = truncf(pyr);
                const float fx = px - ixf;
                const float fy = pyr - iylf;
                const int lin = (int)fmaf(iylf, (float)QDIM, ixf);
                uint2 qw;
                __builtin_memcpy(&qw, &lds[lin], 8);
                const float2 fa = __half22float2(*reinterpret_cast<const __half2*>(&qw.x));
                const float2 fb = __half22float2(*reinterpret_cast<const __half2*>(&qw.y));
                const float gx = 1.f - fx;
                const float h0 = fmaf(fx, fb.x, gx * fa.x);
                const float h1 = fmaf(fx, fb.y, gx * fa.y);
                acc1 = fmaf(1.f - fy, h0, acc1);
                acc1 = fmaf(fy, h1, acc1);
            }
        }
        t += 0.0078125f;                                       // +4/512
    }
    if (s <= sb1) {
        const float px = fmaf(t, dx, bx);
        const float pyr = fmaf(t, dy, by) - B0f;
        if (pyr >= 0.f && pyr < (float)BROWS) {
            const float ixf = truncf(px);
            const float iylf = truncf(pyr);
            const float fx = px - ixf;
            const float fy = pyr - iylf;
            const int lin = (int)fmaf(iylf, (float)QDIM, ixf);
            uint2 qw;
            __builtin_memcpy(&qw, &lds[lin], 8);
            const float2 fa = __half22float2(*reinterpret_cast<const __half2*>(&qw.x));
            const float2 fb = __half22float2(*reinterpret_cast<const __half2*>(&qw.y));
            const float gx = 1.f - fx;
            const float h0 = fmaf(fx, fb.x, gx * fa.x);
            const float h1 = fmaf(fx, fb.y, gx * fa.y);
            acc0 = fmaf(1.f - fy, h0, acc0);
            acc0 = fmaf(fy, h1, acc0);
        }
    }

    float acc = acc0 + acc1;
    acc += __shfl_xor(acc, 1);    // sum the 2 sample-offset lanes
    if (soff == 0 && acc != 0.f) {
        atomicAdd(&sino[rid], acc * b.x);
    }
}

// ---------------------------------------------------------------------------
// Minimal fallback path (tiny workspace): plain projector straight from upd.
// ---------------------------------------------------------------------------
__global__ __launch_bounds__(256) void add_kernel(const float4* __restrict__ x,
                                                  const float4* __restrict__ r,
                                                  float4* __restrict__ upd) {
    int i = blockIdx.x * blockDim.x + threadIdx.x;
    float4 a = x[i];
    float4 b = r[i];
    upd[i] = make_float4(a.x + b.x, a.y + b.y, a.z + b.z, a.w + b.w);
}
__global__ __launch_bounds__(256) void relu_kernel(const float4* __restrict__ upd,
                                                   float4* __restrict__ out) {
    int i = blockIdx.x * blockDim.x + threadIdx.x;
    float4 c = upd[i];
    out[i] = make_float4(fmaxf(c.x, 0.f), fmaxf(c.y, 0.f),
                         fmaxf(c.z, 0.f), fmaxf(c.w, 0.f));
}

__device__ __forceinline__ float sample_plain(const float* __restrict__ img,
                                              int s, float dx, float dy,
                                              float bx, float by, float acc) {
    const float t  = fmaf((float)s, 1.f / (float)N_SAMPLES,
                          0.5f / (float)N_SAMPLES);
    const float px = fmaf(t, dx, bx);
    const float py = fmaf(t, dy, by);
    const float ix0f = floorf(px);
    const float iy0f = floorf(py);
    const float fx = px - ix0f;
    const float fy = py - iy0f;
    const int ix0 = (int)ix0f;
    const int iy0 = (int)iy0f;
    const float gx = ((unsigned)ix0       < (unsigned)IMG_W) ? (1.f - fx) : 0.f;
    const float hx = ((unsigned)(ix0 + 1) < (unsigned)IMG_W) ? fx         : 0.f;
    const float gy = ((unsigned)iy0       < (unsigned)IMG_H) ? (1.f - fy) : 0.f;
    const float hy = ((unsigned)(iy0 + 1) < (unsigned)IMG_H) ? fy         : 0.f;
    const unsigned cx0 = (unsigned)min(max(ix0, 0), IMG_W - 1);
    const unsigned cx1 = (unsigned)min(max(ix0 + 1, 0), IMG_W - 1);
    const unsigned r0  = (unsigned)min(max(iy0, 0), IMG_H - 1) << 9;
    const unsigned r1  = (unsigned)min(max(iy0 + 1, 0), IMG_H - 1) << 9;
    const float v00 = img[r0 + cx0];
    const float v01 = img[r0 + cx1];
    const float v10 = img[r1 + cx0];
    const float v11 = img[r1 + cx1];
    acc = fmaf(v00, gx * gy, acc);
    acc = fmaf(v01, hx * gy, acc);
    acc = fmaf(v10, gx * hy, acc);
    acc = fmaf(v11, hx * hy, acc);
    return acc;
}

__global__ __launch_bounds__(256) void fanproj_plain_kernel(
        const float* __restrict__ img,
        const float* __restrict__ src_pos,
        const float* __restrict__ det_center,
        const float* __restrict__ det_u,
        float* __restrict__ sino) {
    const int wid  = (blockIdx.x * blockDim.x + threadIdx.x) >> 6;
    const int lane = threadIdx.x & 63;
    if (wid >= N_RAYS) return;
    const int v   = wid >> 9;
    const int det = wid & 511;
    const float sx = src_pos[2 * v];
    const float sy = src_pos[2 * v + 1];
    const float u  = ((float)det - 255.5f) * 2.0f;
    const float ex = det_center[2 * v]     + u * det_u[2 * v];
    const float ey = det_center[2 * v + 1] + u * det_u[2 * v + 1];
    const float dx = ex - sx;
    const float dy = ey - sy;
    const float seg = sqrtf(dx * dx + dy * dy);
    const float bx = sx + 255.5f;
    const float by = sy + 255.5f;
    const float lo = -256.5f, hi = 256.5f;
    float t0 = 0.f, t1 = 1.f;
    if (fabsf(dx) > 1e-12f) {
        float ta = (lo - sx) / dx, tb = (hi - sx) / dx;
        t0 = fmaxf(t0, fminf(ta, tb));
        t1 = fminf(t1, fmaxf(ta, tb));
    } else if (sx <= lo || sx >= hi) {
        t1 = -1.f;
    }
    if (fabsf(dy) > 1e-12f) {
        float ta = (lo - sy) / dy, tb = (hi - sy) / dy;
        t0 = fmaxf(t0, fminf(ta, tb));
        t1 = fminf(t1, fmaxf(ta, tb));
    } else if (sy <= lo || sy >= hi) {
        t1 = -1.f;
    }
    int s0 = 0, s1 = -1;
    if (t1 >= t0) {
        s0 = max(0, (int)floorf(t0 * (float)N_SAMPLES - 0.5f) - 1);
        s1 = min(N_SAMPLES - 1, (int)ceilf(t1 * (float)N_SAMPLES - 0.5f) + 1);
    }
    float acc0 = 0.f, acc1 = 0.f;
    int s = s0 + lane;
    for (; s + 64 <= s1; s += 128) {
        acc0 = sample_plain(img, s,      dx, dy, bx, by, acc0);
        acc1 = sample_plain(img, s + 64, dx, dy, bx, by, acc1);
    }
    if (s <= s1) acc0 = sample_plain(img, s, dx, dy, bx, by, acc0);
    float acc = acc0 + acc1;
    #pragma unroll
    for (int off = 32; off >= 1; off >>= 1) acc += __shfl_xor(acc, off);
    if (lane == 0) sino[wid] = acc * seg * (1.0f / (float)N_SAMPLES);
}

// ---------------------------------------------------------------------------
extern "C" void kernel_launch(void* const* d_in, const int* in_sizes, int n_in,
                              void* d_out, int out_size, void* d_ws, size_t ws_size,
                              hipStream_t stream) {
    const float* x          = (const float*)d_in[0];
    const float* reco       = (const float*)d_in[1];
    const float* src_pos    = (const float*)d_in[2];
    const float* det_center = (const float*)d_in[3];
    const float* det_u      = (const float*)d_in[4];

    float* out  = (float*)d_out;
    float* sino = out;                 // [180*512]
    float* relu = out + N_RAYS;        // [512*512]

    const int n4 = IMG_N / 4;          // 65536

    if (ws_size >= 2 * R_BYTES_AL + RAYINFO_BYTES) {
        unsigned* Rrm = (unsigned*)d_ws;
        unsigned* Tcm = (unsigned*)((char*)d_ws + R_BYTES_AL);
        float4*   RA  = (float4*)((char*)d_ws + 2 * R_BYTES_AL);
        float4*   RB  = RA + N_RAYS;
        prep_kernel<<<2 * PACK_BLOCKS + SETUP_BLOCKS, 256, 0, stream>>>(
            x, reco, Rrm, Tcm, relu, src_pos, det_center, det_u, RA, RB, sino);
        fanproj_band_kernel<<<dim3(NBANDS, N_VIEWS), 1024, LDS_BYTES, stream>>>(
            Rrm, Tcm, det_u, RA, RB, sino);
    } else {
        // minimal fallback: upd lives in the relu output region
        float* upd = relu;
        add_kernel<<<n4 / 256, 256, 0, stream>>>(
            (const float4*)x, (const float4*)reco, (float4*)upd);
        fanproj_plain_kernel<<<N_RAYS / 4, 256, 0, stream>>>(
            upd, src_pos, det_center, det_u, sino);
        relu_kernel<<<n4 / 256, 256, 0, stream>>>(
            (const float4*)upd, (float4*)relu);
    }
}

// Round 12
// 36.582 us; speedup vs baseline: 1.2427x; 1.2427x over previous
//
#include <hip/hip_runtime.h>
#include <hip/hip_bf16.h>
#include <hip/hip_fp16.h>

// Problem constants (from reference)
#define IMG_H 512
#define IMG_W 512
#define N_VIEWS 180
#define N_DET 512
#define N_SAMPLES 512

#define N_RAYS (N_VIEWS * N_DET)          // 92160
#define IMG_N (IMG_H * IMG_W)             // 262144

// Row-pair fp16 grid, 8-px zero pad ring:
//   R[(iy+8)*QDIM + (ix+8)] = half2{ I[iy][ix], I[iy+1][ix] }   (4 bytes)
// for ix,iy in [-8, 520], I==0 outside [0,512)^2.
// A bilinear sample at cell (ix,iy) reads R[iy][ix] and R[iy][ix+1]:
// 8 contiguous bytes -> one dword-aligned dwordx2 load, all 4 taps.
// The slab clip widens the sample range by <= ~6.4 px beyond the box, so all
// touched cells lie inside the pad -> no clamping, taps exactly reproduce the
// reference's zero-outside gather.
#define QPAD 8
#define QDIM (IMG_W + 1 + 2 * QPAD)       // 529
#define R_N (QDIM * QDIM)                 // 279841
#define R_BYTES ((size_t)R_N * 4)         // ~1.07 MiB
#define R_BYTES_AL ((R_BYTES + 255) & ~(size_t)255)
#define RAYINFO_BYTES ((size_t)N_RAYS * 32)

#define K_CHUNKS 4
#define PACK_BLOCKS ((R_N + 255) / 256)   // 1094
#define SETUP_BLOCKS (N_RAYS / 256)       // 360

// ---------------------------------------------------------------------------
// k1 (merged prep):
//   blocks [0, PACK_BLOCKS): pack R (row-pair half2) from x+reco; also emit
//     relu(x+reco) (each image pixel owned by exactly one thread).
//   blocks [PACK_BLOCKS, +SETUP_BLOCKS): per-ray setup ->
//     RA[rid]={dx,dy,bx,by}, RB[rid]={segscl,s0,len,0}; zero sino[rid].
// ---------------------------------------------------------------------------
__global__ __launch_bounds__(256) void prep_kernel(
        const float* __restrict__ x, const float* __restrict__ r,
        unsigned* __restrict__ R, float* __restrict__ relu_out,
        const float* __restrict__ src_pos,
        const float* __restrict__ det_center,
        const float* __restrict__ det_u,
        float4* __restrict__ RA, float4* __restrict__ RB,
        float* __restrict__ sino) {
    const int b = blockIdx.x;
    if (b < PACK_BLOCKS) {
        int i = b * 256 + threadIdx.x;
        if (i >= R_N) return;
        int row = i / QDIM;
        int col = i - row * QDIM;
        int yy = row - QPAD;   // taps (yy, yy+1) at x = xx
        int xx = col - QPAD;
        float v0 = 0.f, v1 = 0.f;
        if ((unsigned)xx < (unsigned)IMG_W) {
            if ((unsigned)yy < (unsigned)IMG_H) {
                int idx = yy * IMG_W + xx;
                v0 = x[idx] + r[idx];
            }
            if ((unsigned)(yy + 1) < (unsigned)IMG_H) {
                int idx = (yy + 1) * IMG_W + xx;
                v1 = x[idx] + r[idx];
            }
        }
        __half2 h = __floats2half2_rn(v0, v1);
        R[i] = *reinterpret_cast<unsigned*>(&h);
        if ((unsigned)xx < (unsigned)IMG_W && (unsigned)yy < (unsigned)IMG_H)
            relu_out[yy * IMG_W + xx] = fmaxf(v0, 0.f);
        return;
    }

    // ---- ray setup part ----
    const int rid = (b - PACK_BLOCKS) * 256 + threadIdx.x;
    const int v   = rid >> 9;
    const int det = rid & 511;

    const float sx = src_pos[2 * v];
    const float sy = src_pos[2 * v + 1];
    const float u  = ((float)det - 255.5f) * 2.0f;   // DET_SPACING = 2
    const float ex = det_center[2 * v]     + u * det_u[2 * v];
    const float ey = det_center[2 * v + 1] + u * det_u[2 * v + 1];

    const float dx = ex - sx;
    const float dy = ey - sy;
    const float segscl = sqrtf(dx * dx + dy * dy) * (1.0f / (float)N_SAMPLES);

    // slab clip of t in [0,1] against world box (-256.5, 256.5)^2 (perf only;
    // widened range overshoots the box by <= 6.4 px < QPAD)
    const float lo = -256.5f, hi = 256.5f;
    float t0 = 0.f, t1 = 1.f;
    if (fabsf(dx) > 1e-12f) {
        float ta = (lo - sx) / dx, tb = (hi - sx) / dx;
        t0 = fmaxf(t0, fminf(ta, tb));
        t1 = fminf(t1, fmaxf(ta, tb));
    } else if (sx <= lo || sx >= hi) {
        t1 = -1.f;
    }
    if (fabsf(dy) > 1e-12f) {
        float ta = (lo - sy) / dy, tb = (hi - sy) / dy;
        t0 = fmaxf(t0, fminf(ta, tb));
        t1 = fminf(t1, fmaxf(ta, tb));
    } else if (sy <= lo || sy >= hi) {
        t1 = -1.f;
    }
    int s0 = 0, len = 0;
    if (t1 >= t0) {
        s0 = max(0, (int)floorf(t0 * (float)N_SAMPLES - 0.5f) - 1);
        int s1 = min(N_SAMPLES - 1, (int)ceilf(t1 * (float)N_SAMPLES - 0.5f) + 1);
        len = s1 - s0 + 1;
        if (len < 0) len = 0;
    }
    RA[rid] = make_float4(dx, dy, sx + 255.5f + (float)QPAD,
                                  sy + 255.5f + (float)QPAD);
    RB[rid] = make_float4(segscl, (float)s0, (float)len, 0.f);
    sino[rid] = 0.f;
}

// ---------------------------------------------------------------------------
// row-pair bilinear sample: ONE 8B (dword-aligned) load, no clamp, no mask.
// px,py in (0.6, 526.4) -> trunc == floor, indices in-bounds.
// ---------------------------------------------------------------------------
__device__ __forceinline__ float sample_h(const unsigned* __restrict__ R,
                                          float t, float dx, float dy,
                                          float bx, float by, float acc) {
    const float px = fmaf(t, dx, bx);
    const float py = fmaf(t, dy, by);
    const float ixf = truncf(px);
    const float iyf = truncf(py);
    const float fx = px - ixf;
    const float fy = py - iyf;
    const int lin = (int)iyf * QDIM + (int)ixf;

    uint2 qw;
    __builtin_memcpy(&qw, R + lin, 8);   // {v00,v10}, {v01,v11}
    const float2 fa = __half22float2(*reinterpret_cast<const __half2*>(&qw.x));
    const float2 fb = __half22float2(*reinterpret_cast<const __half2*>(&qw.y));

    const float gx = 1.f - fx;
    const float h0 = fmaf(fx, fb.x, gx * fa.x);   // top row lerp
    const float h1 = fmaf(fx, fb.y, gx * fa.y);   // bottom row lerp
    acc = fmaf(1.f - fy, h0, acc);
    acc = fmaf(fy, h1, acc);
    return acc;
}

// ---------------------------------------------------------------------------
// k2: fan-beam projection, 2D lane tiling (16 dets x 4 sample-offsets).
//   block = 256 threads = 64 dets; grid = (1440, K_CHUNKS).
//   Per-ray partial reduced via shfl_xor(16/32); lane soff==0 does one atomic.
// ---------------------------------------------------------------------------
__global__ __launch_bounds__(256) void fanproj_tile_kernel(
        const unsigned* __restrict__ R,
        const float4* __restrict__ RA, const float4* __restrict__ RB,
        float* __restrict__ sino) {
    const int tix  = threadIdx.x;
    const int lane = tix & 63;
    const int dsub = lane & 15;
    const int soff = lane >> 4;                       // 0..3
    const int rid  = blockIdx.x * 64 + ((tix >> 6) << 4) + dsub;
    const int chunk = blockIdx.y;

    const float4 a = RA[rid];
    const float4 b = RB[rid];
    const float dx = a.x, dy = a.y, bx = a.z, by = a.w;
    const int s0  = (int)b.y;
    const int len = (int)b.z;
    const int c0 = s0 + ((len * chunk) >> 2);
    const int c1 = s0 + ((len * (chunk + 1)) >> 2) - 1;

    int s = c0 + soff;
    float t = ((float)s + 0.5f) * (1.0f / (float)N_SAMPLES);  // exact
    float acc0 = 0.f, acc1 = 0.f;
    for (; s + 4 <= c1; s += 8) {
        acc0 = sample_h(R, t,               dx, dy, bx, by, acc0);
        acc1 = sample_h(R, t + 0.0078125f,  dx, dy, bx, by, acc1); // +4/512
        t += 0.015625f;                                            // +8/512
    }
    if (s <= c1) acc0 = sample_h(R, t, dx, dy, bx, by, acc0);

    float acc = acc0 + acc1;
    acc += __shfl_xor(acc, 16);   // sum over the 4 sample-offset groups
    acc += __shfl_xor(acc, 32);
    if (soff == 0) {
        const float res = acc * b.x;
        if (res != 0.f) atomicAdd(&sino[rid], res);
    }
}

// ---------------------------------------------------------------------------
// Minimal fallback path (tiny workspace): plain projector straight from upd.
// ---------------------------------------------------------------------------
__global__ __launch_bounds__(256) void add_kernel(const float4* __restrict__ x,
                                                  const float4* __restrict__ r,
                                                  float4* __restrict__ upd) {
    int i = blockIdx.x * blockDim.x + threadIdx.x;
    float4 a = x[i];
    float4 b = r[i];
    upd[i] = make_float4(a.x + b.x, a.y + b.y, a.z + b.z, a.w + b.w);
}
__global__ __launch_bounds__(256) void relu_kernel(const float4* __restrict__ upd,
                                                   float4* __restrict__ out) {
    int i = blockIdx.x * blockDim.x + threadIdx.x;
    float4 c = upd[i];
    out[i] = make_float4(fmaxf(c.x, 0.f), fmaxf(c.y, 0.f),
                         fmaxf(c.z, 0.f), fmaxf(c.w, 0.f));
}

__device__ __forceinline__ float sample_plain(const float* __restrict__ img,
                                              int s, float dx, float dy,
                                              float bx, float by, float acc) {
    const float t  = fmaf((float)s, 1.f / (float)N_SAMPLES,
                          0.5f / (float)N_SAMPLES);
    const float px = fmaf(t, dx, bx);
    const float py = fmaf(t, dy, by);
    const float ix0f = floorf(px);
    const float iy0f = floorf(py);
    const float fx = px - ix0f;
    const float fy = py - iy0f;
    const int ix0 = (int)ix0f;
    const int iy0 = (int)iy0f;
    const float gx = ((unsigned)ix0       < (unsigned)IMG_W) ? (1.f - fx) : 0.f;
    const float hx = ((unsigned)(ix0 + 1) < (unsigned)IMG_W) ? fx         : 0.f;
    const float gy = ((unsigned)iy0       < (unsigned)IMG_H) ? (1.f - fy) : 0.f;
    const float hy = ((unsigned)(iy0 + 1) < (unsigned)IMG_H) ? fy         : 0.f;
    const unsigned cx0 = (unsigned)min(max(ix0, 0), IMG_W - 1);
    const unsigned cx1 = (unsigned)min(max(ix0 + 1, 0), IMG_W - 1);
    const unsigned r0  = (unsigned)min(max(iy0, 0), IMG_H - 1) << 9;
    const unsigned r1  = (unsigned)min(max(iy0 + 1, 0), IMG_H - 1) << 9;
    const float v00 = img[r0 + cx0];
    const float v01 = img[r0 + cx1];
    const float v10 = img[r1 + cx0];
    const float v11 = img[r1 + cx1];
    acc = fmaf(v00, gx * gy, acc);
    acc = fmaf(v01, hx * gy, acc);
    acc = fmaf(v10, gx * hy, acc);
    acc = fmaf(v11, hx * hy, acc);
    return acc;
}

__global__ __launch_bounds__(256) void fanproj_plain_kernel(
        const float* __restrict__ img,
        const float* __restrict__ src_pos,
        const float* __restrict__ det_center,
        const float* __restrict__ det_u,
        float* __restrict__ sino) {
    const int wid  = (blockIdx.x * blockDim.x + threadIdx.x) >> 6;
    const int lane = threadIdx.x & 63;
    if (wid >= N_RAYS) return;
    const int v   = wid >> 9;
    const int det = wid & 511;
    const float sx = src_pos[2 * v];
    const float sy = src_pos[2 * v + 1];
    const float u  = ((float)det - 255.5f) * 2.0f;
    const float ex = det_center[2 * v]     + u * det_u[2 * v];
    const float ey = det_center[2 * v + 1] + u * det_u[2 * v + 1];
    const float dx = ex - sx;
    const float dy = ey - sy;
    const float seg = sqrtf(dx * dx + dy * dy);
    const float bx = sx + 255.5f;
    const float by = sy + 255.5f;
    const float lo = -256.5f, hi = 256.5f;
    float t0 = 0.f, t1 = 1.f;
    if (fabsf(dx) > 1e-12f) {
        float ta = (lo - sx) / dx, tb = (hi - sx) / dx;
        t0 = fmaxf(t0, fminf(ta, tb));
        t1 = fminf(t1, fmaxf(ta, tb));
    } else if (sx <= lo || sx >= hi) {
        t1 = -1.f;
    }
    if (fabsf(dy) > 1e-12f) {
        float ta = (lo - sy) / dy, tb = (hi - sy) / dy;
        t0 = fmaxf(t0, fminf(ta, tb));
        t1 = fminf(t1, fmaxf(ta, tb));
    } else if (sy <= lo || sy >= hi) {
        t1 = -1.f;
    }
    int s0 = 0, s1 = -1;
    if (t1 >= t0) {
        s0 = max(0, (int)floorf(t0 * (float)N_SAMPLES - 0.5f) - 1);
        s1 = min(N_SAMPLES - 1, (int)ceilf(t1 * (float)N_SAMPLES - 0.5f) + 1);
    }
    float acc0 = 0.f, acc1 = 0.f;
    int s = s0 + lane;
    for (; s + 64 <= s1; s += 128) {
        acc0 = sample_plain(img, s,      dx, dy, bx, by, acc0);
        acc1 = sample_plain(img, s + 64, dx, dy, bx, by, acc1);
    }
    if (s <= s1) acc0 = sample_plain(img, s, dx, dy, bx, by, acc0);
    float acc = acc0 + acc1;
    #pragma unroll
    for (int off = 32; off >= 1; off >>= 1) acc += __shfl_xor(acc, off);
    if (lane == 0) sino[wid] = acc * seg * (1.0f / (float)N_SAMPLES);
}

// ---------------------------------------------------------------------------
extern "C" void kernel_launch(void* const* d_in, const int* in_sizes, int n_in,
                              void* d_out, int out_size, void* d_ws, size_t ws_size,
                              hipStream_t stream) {
    const float* x          = (const float*)d_in[0];
    const float* reco       = (const float*)d_in[1];
    const float* src_pos    = (const float*)d_in[2];
    const float* det_center = (const float*)d_in[3];
    const float* det_u      = (const float*)d_in[4];

    float* out  = (float*)d_out;
    float* sino = out;                 // [180*512]
    float* relu = out + N_RAYS;        // [512*512]

    const int n4 = IMG_N / 4;          // 65536

    if (ws_size >= R_BYTES_AL + RAYINFO_BYTES) {
        unsigned* R  = (unsigned*)d_ws;                        // ~1.07 MiB
        float4*   RA = (float4*)((char*)d_ws + R_BYTES_AL);
        float4*   RB = RA + N_RAYS;
        prep_kernel<<<PACK_BLOCKS + SETUP_BLOCKS, 256, 0, stream>>>(
            x, reco, R, relu, src_pos, det_center, det_u, RA, RB, sino);
        fanproj_tile_kernel<<<dim3(N_RAYS / 64, K_CHUNKS), 256, 0, stream>>>(
            R, RA, RB, sino);
    } else {
        // minimal fallback: upd lives in the relu output region
        float* upd = relu;
        add_kernel<<<n4 / 256, 256, 0, stream>>>(
            (const float4*)x, (const float4*)reco, (float4*)upd);
        fanproj_plain_kernel<<<N_RAYS / 4, 256, 0, stream>>>(
            upd, src_pos, det_center, det_u, sino);
        relu_kernel<<<n4 / 256, 256, 0, stream>>>(
            (const float4*)upd, (float4*)relu);
    }
}